// Round 11
// baseline (316.033 us; speedup 1.0000x reference)
//
#include <hip/hip_runtime.h>

// Problem constants (match reference)
#define N_PTS   1000000
#define C_DIM   128
#define B_DIM   8
#define Y_DIM   468
#define X_DIM   468
#define YX      (Y_DIM * X_DIM)         // 219024
#define KSPACE  (B_DIM * YX)            // 1752192 dense key space

// Scan config
#define WG   256
#define EPT  8
#define EPB  (WG * EPT)                 // 2048 elements per scan block
#define NBLK ((KSPACE + EPB - 1) / EPB) // 856

// 3-field packed scan element: [0:21) point-count, [21:42) unique-count, [42:63) multi-count
#define F_BITS 21
#define F_MASK 0x1FFFFFu
#define SINGLE_FLAG (1ull << 63)

#define PAD_BLOCKS 1024

// native vector type for nontemporal builtins (HIP's float4 is a class)
typedef float f4 __attribute__((ext_vector_type(4)));

__device__ __forceinline__ unsigned long long shfl_up_u64(unsigned long long v, int delta) {
    unsigned lo = (unsigned)v;
    unsigned hi = (unsigned)(v >> 32);
    lo = __shfl_up(lo, delta, 64);
    hi = __shfl_up(hi, delta, 64);
    return ((unsigned long long)hi << 32) | lo;
}

// ---------------------------------------------------------------- histogram + key cache
__global__ void hist_kernel(const int* __restrict__ idx, unsigned* __restrict__ cnt,
                            unsigned* __restrict__ keys, int n) {
    int i = blockIdx.x * blockDim.x + threadIdx.x;
    if (i >= n) return;
    int4 v = ((const int4*)idx)[i];          // (b, z, y, x)
    unsigned key = (unsigned)(v.x * YX + v.z * X_DIM + v.w);
    keys[i] = key;
    atomicAdd(&cnt[key], 1u);
}

// ---------------------------------------------------------------- scan pass 1: per-block exclusive scan of packed (count|unique|multi)
// pairs[k] = exclusive prefix within block, bit63 = (cnt[k]==1)
__global__ void scan1_kernel(const unsigned* __restrict__ cnt,
                             unsigned long long* __restrict__ pairs,
                             unsigned long long* __restrict__ bsums, int K) {
    int base = blockIdx.x * EPB + threadIdx.x * EPT;
    unsigned long long p[EPT];
    unsigned cc[EPT];
    unsigned long long run = 0;
#pragma unroll
    for (int j = 0; j < EPT; ++j) {
        int k = base + j;
        unsigned c = (k < K) ? cnt[k] : 0u;
        cc[j] = c;
        unsigned long long pr = (unsigned long long)c
                              | ((unsigned long long)(c ? 1u : 0u) << F_BITS)
                              | ((unsigned long long)(c >= 2u ? 1u : 0u) << (2 * F_BITS));
        p[j] = run;                           // exclusive within thread
        run += pr;
    }
    unsigned long long tot = run;
    // inclusive wave scan of thread totals
    int lane = threadIdx.x & 63;
    unsigned long long v = tot;
#pragma unroll
    for (int d = 1; d < 64; d <<= 1) {
        unsigned long long nv = shfl_up_u64(v, d);
        if (lane >= d) v += nv;
    }
    __shared__ unsigned long long wsum[WG / 64];
    int wid = threadIdx.x >> 6;
    if (lane == 63) wsum[wid] = v;
    __syncthreads();
    unsigned long long wexcl = 0;
    for (int w = 0; w < wid; ++w) wexcl += wsum[w];
    unsigned long long texcl = wexcl + v - tot;   // exclusive across threads in block
#pragma unroll
    for (int j = 0; j < EPT; ++j) {
        int k = base + j;
        if (k < K)
            pairs[k] = (texcl + p[j]) | (cc[j] == 1u ? SINGLE_FLAG : 0ull);
    }
    if (threadIdx.x == WG - 1) bsums[blockIdx.x] = wexcl + v;  // block total
}

// ---------------------------------------------------------------- scan pass 2: exclusive scan of block sums (single block, nb <= 1024)
__global__ void scan2_kernel(unsigned long long* __restrict__ bsums, int nb) {
    int t = threadIdx.x;
    unsigned long long orig = (t < nb) ? bsums[t] : 0ull;
    unsigned long long v = orig;
    int lane = t & 63;
#pragma unroll
    for (int d = 1; d < 64; d <<= 1) {
        unsigned long long nv = shfl_up_u64(v, d);
        if (lane >= d) v += nv;
    }
    __shared__ unsigned long long ws[1024 / 64];
    int wid = t >> 6;
    if (lane == 63) ws[wid] = v;
    __syncthreads();
    unsigned long long wexcl = 0;
    for (int w = 0; w < wid; ++w) wexcl += ws[w];
    if (t < nb) bsums[t] = wexcl + v - orig;      // exclusive
    if (t == 1023) {                              // grand total -> bsums[nb]
        unsigned long long tt = 0;
        for (int w = 0; w < 1024 / 64; ++w) tt += ws[w];
        bsums[nb] = tt;
    }
}

// ---------------------------------------------------------------- heavy fused kernel: [uniq | point | pad] block ranges
// uniq blocks: per-key counts from ADJACENT scan prefixes (no cnt read ->
//   no race with point blocks' atomicSub cursor). Sequential outI + wl.
// point blocks: 16 points/wave (4 lanes/point, 8 f4 slots each);
//   singleton row copy OR pid scatter.
// pad blocks: stream zero rows [nU, n).
__global__ void __launch_bounds__(256)
heavy_kernel(const float* __restrict__ feat, const unsigned* __restrict__ keys,
             const unsigned long long* __restrict__ pairs,
             const unsigned long long* __restrict__ bsums,
             unsigned* __restrict__ cnt, unsigned* __restrict__ pids,
             uint4* __restrict__ wl,
             float* __restrict__ outF, float* __restrict__ outI,
             int n, int K, int pointBlocks) {
    int tid  = threadIdx.x;
    int lane = tid & 63;
    int wid  = tid >> 6;
    int bid  = blockIdx.x;

    if (bid < NBLK) {
        // ---- uniq range ----
        int base = bid * EPB + tid * EPT;
        if (base >= K) return;
        unsigned long long bofs = bsums[bid];     // same scan-block for keys base..base+7
        unsigned long long P[EPT + 1];
#pragma unroll
        for (int j = 0; j < EPT; ++j) {
            int k = base + j;
            P[j] = (k < K) ? ((pairs[k] & ~SINGLE_FLAG) + bofs) : bsums[NBLK];
        }
        {
            int k = base + EPT;                   // neighbor (crosses scan-block only at tid==255)
            P[EPT] = (k < K) ? ((pairs[k] & ~SINGLE_FLAG) + bsums[k >> 11]) : bsums[NBLK];
        }
#pragma unroll
        for (int j = 0; j < EPT; ++j) {
            int k = base + j;
            if (k >= K) break;
            unsigned long long diff = P[j + 1] - P[j];   // monotonic fields: no borrow
            unsigned c = (unsigned)(diff & F_MASK);
            if (c == 0) continue;
            unsigned rank = (unsigned)((P[j] >> F_BITS) & F_MASK);
            unsigned bb  = (unsigned)k / YX;
            unsigned rem = (unsigned)k % YX;
            outI[(size_t)rank * 3 + 0] = (float)bb;
            outI[(size_t)rank * 3 + 1] = (float)(rem / X_DIM);
            outI[(size_t)rank * 3 + 2] = (float)(rem % X_DIM);
            if (c >= 2) {
                unsigned start = (unsigned)(P[j] & F_MASK);
                unsigned mslot = (unsigned)((P[j] >> (2 * F_BITS)) & F_MASK);
                wl[mslot] = make_uint4(start, start + c, (unsigned)k, rank);
            }
        }
    } else if (bid < NBLK + pointBlocks) {
        // ---- point range: 16 points/wave (4 lanes/point, 8 f4 slots each) ----
        int e   = lane >> 2;
        int sub = lane & 3;
        long p = (long)(bid - NBLK) * 64 + wid * 16 + e;
        if (p >= n) return;
        unsigned key = keys[p];
        unsigned long long pr = pairs[key];
        if (pr >> 63) {                   // singleton: copy own row to out[rank]
            pr += bsums[key >> 11];
            unsigned rank = (unsigned)((pr >> F_BITS) & F_MASK);
            const f4* src = (const f4*)(feat + (size_t)p * C_DIM);
            f4*       dst = (f4*)(outF + (size_t)rank * C_DIM);
            f4 v0 = __builtin_nontemporal_load(src + sub);
            f4 v1 = __builtin_nontemporal_load(src + sub + 4);
            f4 v2 = __builtin_nontemporal_load(src + sub + 8);
            f4 v3 = __builtin_nontemporal_load(src + sub + 12);
            f4 v4 = __builtin_nontemporal_load(src + sub + 16);
            f4 v5 = __builtin_nontemporal_load(src + sub + 20);
            f4 v6 = __builtin_nontemporal_load(src + sub + 24);
            f4 v7 = __builtin_nontemporal_load(src + sub + 28);
            __builtin_nontemporal_store(v0, dst + sub);
            __builtin_nontemporal_store(v1, dst + sub + 4);
            __builtin_nontemporal_store(v2, dst + sub + 8);
            __builtin_nontemporal_store(v3, dst + sub + 12);
            __builtin_nontemporal_store(v4, dst + sub + 16);
            __builtin_nontemporal_store(v5, dst + sub + 20);
            __builtin_nontemporal_store(v6, dst + sub + 24);
            __builtin_nontemporal_store(v7, dst + sub + 28);
        } else if (sub == 0) {            // multi: scatter pid (cnt doubles as cursor)
            unsigned start = (unsigned)((pr + bsums[key >> 11]) & F_MASK);
            unsigned off = atomicSub(&cnt[key], 1u) - 1u;    // c-1, ..., 0
            pids[start + off] = (unsigned)p;
        }
    } else {
        // ---- pad range: rows [nU, n) -> zeros + (-1, 467, 467) ----
        int e   = lane >> 2;
        int sub = lane & 3;
        unsigned long long tot = bsums[NBLK];
        long nU = (long)((tot >> F_BITS) & F_MASK);
        long pb = bid - NBLK - pointBlocks;
        long base   = nU + pb * 64 + wid * 16 + e;
        long stride = (long)PAD_BLOCKS * 64;
        f4 z = (f4)(0.f);
        for (long r = base; r < n; r += stride) {
            f4* dst = (f4*)(outF + (size_t)r * C_DIM);
            __builtin_nontemporal_store(z, dst + sub);
            __builtin_nontemporal_store(z, dst + sub + 4);
            __builtin_nontemporal_store(z, dst + sub + 8);
            __builtin_nontemporal_store(z, dst + sub + 12);
            __builtin_nontemporal_store(z, dst + sub + 16);
            __builtin_nontemporal_store(z, dst + sub + 20);
            __builtin_nontemporal_store(z, dst + sub + 24);
            __builtin_nontemporal_store(z, dst + sub + 28);
            if (sub == 0) {
                outI[(size_t)r * 3 + 0] = -1.0f;
                outI[(size_t)r * 3 + 1] = 467.0f;   // (-1 % YX) // X per numpy floor-mod
                outI[(size_t)r * 3 + 2] = 467.0f;
            }
        }
    }
}

// ---------------------------------------------------------------- multi gather+sum: 8 rows/wave (8 lanes/row, 4 f4 slots), paired pids
__global__ void __launch_bounds__(256)
multi_kernel(const float* __restrict__ feat, const unsigned* __restrict__ pointIds,
             const uint4* __restrict__ wl,
             const unsigned long long* __restrict__ total,
             float* __restrict__ outF) {
    int lane = threadIdx.x & 63;
    int wid  = threadIdx.x >> 6;
    int rq   = lane >> 3;                 // row within wave's 8
    int sub  = lane & 7;                  // f4 slots sub, sub+8, sub+16, sub+24
    long m = (long)(((*total) >> (2 * F_BITS)) & F_MASK);
    long base   = (long)blockIdx.x * 32 + wid * 8 + rq;
    long stride = (long)gridDim.x * 32;
    for (long r = base; r < m; r += stride) {
        uint4 d = wl[r];
        f4 a0 = (f4)(0.f), a1 = (f4)(0.f), a2 = (f4)(0.f), a3 = (f4)(0.f);
        unsigned j = d.x, e = d.y;
        for (; j + 1 < e; j += 2) {       // paired: 8 independent f4 loads in flight
            unsigned p0 = pointIds[j];
            unsigned p1 = pointIds[j + 1];
            const f4* s0 = (const f4*)(feat + (size_t)p0 * C_DIM);
            const f4* s1 = (const f4*)(feat + (size_t)p1 * C_DIM);
            f4 v00 = __builtin_nontemporal_load(s0 + sub);
            f4 v01 = __builtin_nontemporal_load(s0 + sub + 8);
            f4 v02 = __builtin_nontemporal_load(s0 + sub + 16);
            f4 v03 = __builtin_nontemporal_load(s0 + sub + 24);
            f4 v10 = __builtin_nontemporal_load(s1 + sub);
            f4 v11 = __builtin_nontemporal_load(s1 + sub + 8);
            f4 v12 = __builtin_nontemporal_load(s1 + sub + 16);
            f4 v13 = __builtin_nontemporal_load(s1 + sub + 24);
            a0 += v00 + v10;
            a1 += v01 + v11;
            a2 += v02 + v12;
            a3 += v03 + v13;
        }
        if (j < e) {
            unsigned p0 = pointIds[j];
            const f4* s0 = (const f4*)(feat + (size_t)p0 * C_DIM);
            a0 += __builtin_nontemporal_load(s0 + sub);
            a1 += __builtin_nontemporal_load(s0 + sub + 8);
            a2 += __builtin_nontemporal_load(s0 + sub + 16);
            a3 += __builtin_nontemporal_load(s0 + sub + 24);
        }
        f4* dst = (f4*)(outF + (size_t)d.w * C_DIM);
        __builtin_nontemporal_store(a0, dst + sub);
        __builtin_nontemporal_store(a1, dst + sub + 8);
        __builtin_nontemporal_store(a2, dst + sub + 16);
        __builtin_nontemporal_store(a3, dst + sub + 24);
    }
}

extern "C" void kernel_launch(void* const* d_in, const int* in_sizes, int n_in,
                              void* d_out, int out_size, void* d_ws, size_t ws_size,
                              hipStream_t stream) {
    const float* feat = (const float*)d_in[0];
    const int*   idx  = (const int*)d_in[1];
    const int n = in_sizes[0] / C_DIM;   // 1,000,000
    const int K = KSPACE;

    // workspace layout (256B aligned slices)
    char* ws = (char*)d_ws;
    size_t off = 0;
    auto take = [&](size_t bytes) {
        size_t cur = off;
        off = (off + bytes + 255) & ~(size_t)255;
        return cur;
    };
    size_t o_cnt    = take((size_t)K * 4);        // count per key (reused as scatter cursor)
    size_t o_keys   = take((size_t)n * 4);        // cached keys per point
    size_t o_pairs  = take((size_t)K * 8);        // packed scan prefixes + singleton flag
    size_t o_bsums  = take((size_t)(NBLK + 1) * 8);
    size_t o_pids   = take((size_t)n * 4);        // point ids (multi buckets only)
    size_t o_wl     = take((size_t)(n / 2 + 1) * 16);  // worklist {start,end,key,rank}

    unsigned*           cnt    = (unsigned*)(ws + o_cnt);
    unsigned*           keys   = (unsigned*)(ws + o_keys);
    unsigned long long* pairs  = (unsigned long long*)(ws + o_pairs);
    unsigned long long* bsums  = (unsigned long long*)(ws + o_bsums);
    unsigned*           pids   = (unsigned*)(ws + o_pids);
    uint4*              wl     = (uint4*)(ws + o_wl);

    float* outF = (float*)d_out;
    float* outI = outF + (size_t)n * C_DIM;

    // 1. zero cnt (fill-rate)
    hipMemsetAsync(cnt, 0, (size_t)K * 4, stream);
    // 2. histogram + cache keys
    hist_kernel<<<(n + 255) / 256, 256, 0, stream>>>(idx, cnt, keys, n);
    // 3-4. two-level exclusive scan of packed (count|unique|multi)
    scan1_kernel<<<NBLK, WG, 0, stream>>>(cnt, pairs, bsums, K);
    scan2_kernel<<<1, 1024, 0, stream>>>(bsums, NBLK);
    // 5. fused heavy pass: [uniq | point copy/scatter | pad]
    {
        int pointBlocks = (n + 63) / 64;
        heavy_kernel<<<NBLK + pointBlocks + PAD_BLOCKS, 256, 0, stream>>>(
            feat, keys, pairs, bsums, cnt, pids, wl, outF, outI, n, K, pointBlocks);
    }
    // 6. multi gather+sum (8 rows/wave; 8192 blocks ~= one sweep of ~197K rows)
    multi_kernel<<<8192, 256, 0, stream>>>(feat, pids, wl, bsums + NBLK, outF);
}